// Round 15
// baseline (263.075 us; speedup 1.0000x reference)
//
#include <hip/hip_runtime.h>
#include <hip/hip_bf16.h>
#include <math.h>

// MambaBlock v23: gemm1 de-phased.
//  R14 falsified "gemm1 VALU-bound" (gelu op-halving left VALUBusy at 57%
//  and time unchanged) -> it's phase-serialization: 8 barriers/block.
//  New gemm1: 64x64 tile, As+Bs staged ONCE (K=192 fits LDS), 6 K-steps
//  uninterrupted, 2 barriers total, acc[4]=16 AGPR, grid 6144 XCD-grouped
//  (12 n-tiles per pixel-tile consecutive per XCD). Same K order -> bit
//  identical. Everything else = v22. Dispatches: 6.

#define DEV static __device__ __forceinline__

constexpr int Bn = 8, Dm = 192, Ln = 4096, Sn = 64, Hd = 768;

typedef __attribute__((ext_vector_type(8))) short bf16x8;
typedef __attribute__((ext_vector_type(4))) float f32x4;

DEV short f2b(float x) {
  __hip_bfloat16 h = __float2bfloat16(x);
  return *(short*)&h;
}

DEV float b2f(short x) {
  __hip_bfloat16 h = *(__hip_bfloat16*)&x;
  return __bfloat162float(h);
}

// ---- K0: weight f32 -> bf16 conversion -------------------------------------
__global__ __launch_bounds__(256) void k_weights(
    const float* __restrict__ dt_w, const float* __restrict__ B_w,
    const float* __restrict__ C_w, const float* __restrict__ xp_w,
    const float* __restrict__ out_w, const float* __restrict__ w1,
    const float* __restrict__ w2, short* __restrict__ wb) {
  for (int i = blockIdx.x * 256 + threadIdx.x; i < 89088; i += 64 * 256) {
    const float4* src;
    if (i < 3072)       src = (const float4*)dt_w + i;
    else if (i < 6144)  src = (const float4*)B_w + (i - 3072);
    else if (i < 9216)  src = (const float4*)C_w + (i - 6144);
    else if (i < 12288) src = (const float4*)xp_w + (i - 9216);
    else if (i < 15360) src = (const float4*)out_w + (i - 12288);
    else if (i < 52224) src = (const float4*)w1 + (i - 15360);
    else                src = (const float4*)w2 + (i - 52224);
    float4 v = *src;
    int o = i * 4;
    wb[o] = f2b(v.x); wb[o + 1] = f2b(v.y); wb[o + 2] = f2b(v.z); wb[o + 3] = f2b(v.w);
  }
}

// ---- K1: fused LN1+ssmLN + proj GEMM + SSM epilogue + scan ph1 -------------
__global__ __launch_bounds__(256, 3) void k_fproj(
    const float* __restrict__ x,
    const float* __restrict__ g1, const float* __restrict__ b1,
    const float* __restrict__ g2, const float* __restrict__ b2,
    short* __restrict__ xln1b,
    const short* __restrict__ wcat,
    const float* __restrict__ dt_b, const float* __restrict__ xp_b,
    const float* __restrict__ A_log, float* __restrict__ aA, unsigned* __restrict__ bxc,
    float* __restrict__ sums) {
  __shared__ __align__(16) float R1f[8320];       // 33.3 KB: As (25.6K) / aAs+bxs
  __shared__ __align__(16) short R2s[128 * 72];   // 18.4 KB: Bs half / partP+H
  short* As = (short*)R1f;     // [64][200] bf16 xn tile
  short* Bs = R2s;             // [128][72] bf16 wcat half
  int m0 = blockIdx.x * 64, tid = threadIdx.x;
  int b = m0 >> 12, l0 = m0 & 4095;
  {
    int pix = tid >> 2, part = tid & 3, c0 = part * 48;
    const float* xb = x + (size_t)b * Dm * Ln + l0 + pix;
    float v[48];
    float s1 = 0.f, q1 = 0.f;
#pragma unroll
    for (int j = 0; j < 48; j++) {
      float t = xb[(size_t)(c0 + j) * Ln];
      v[j] = t; s1 += t; q1 += t * t;
    }
    s1 += __shfl_xor(s1, 1); s1 += __shfl_xor(s1, 2);
    q1 += __shfl_xor(q1, 1); q1 += __shfl_xor(q1, 2);
    float m = s1 * (1.f / 192.f);
    float inv = rsqrtf(q1 * (1.f / 192.f) - m * m + 1e-5f);
    float s2 = 0.f, q2 = 0.f;
#pragma unroll
    for (int j = 0; j < 48; j++) {
      float y = (v[j] - m) * inv * g1[c0 + j] + b1[c0 + j];
      v[j] = y; s2 += y; q2 += y * y;
    }
    s2 += __shfl_xor(s2, 1); s2 += __shfl_xor(s2, 2);
    q2 += __shfl_xor(q2, 1); q2 += __shfl_xor(q2, 2);
    float m2 = s2 * (1.f / 192.f);
    float inv2 = rsqrtf(q2 * (1.f / 192.f) - m2 * m2 + 1e-5f);
    size_t base = (size_t)(m0 + pix) * Dm + c0;
#pragma unroll
    for (int j = 0; j < 48; j += 8) {
      int4 yo, no;
      short* yp = (short*)&yo; short* np = (short*)&no;
#pragma unroll
      for (int k = 0; k < 8; k++) {
        float y = v[j + k];
        yp[k] = f2b(y);
        np[k] = f2b((y - m2) * inv2 * g2[c0 + j + k] + b2[c0 + j + k]);
      }
      *(int4*)&xln1b[base + j] = yo;
      *(int4*)&As[pix * 200 + c0 + j] = no;
    }
  }
  __syncthreads();
  int lane = tid & 63, l16 = lane & 15, quad = lane >> 4, w = tid >> 6;
  f32x4 acc[16] = {};
  for (int kt = 0; kt < 3; kt++) {
    int kb = kt * 64;
#pragma unroll
    for (int nh = 0; nh < 2; nh++) {
      for (int i = tid; i < 1024; i += 256) {
        int row = i >> 3, c8 = (i & 7) * 8;
        *(float4*)&Bs[row * 72 + c8] =
            *(const float4*)&wcat[(size_t)(nh * 128 + row) * 192 + kb + c8];
      }
      __syncthreads();
#pragma unroll
      for (int ks = 0; ks < 2; ks++) {
        int ko = ks * 32 + quad * 8;
        bf16x8 a0 = *(const bf16x8*)&As[(w * 16 + l16) * 200 + kb + ko];
        bf16x8 bfr[8];
#pragma unroll
        for (int j = 0; j < 8; j++) bfr[j] = *(const bf16x8*)&Bs[(j * 16 + l16) * 72 + ko];
#pragma unroll
        for (int j = 0; j < 8; j++)
          acc[nh * 8 + j] = __builtin_amdgcn_mfma_f32_16x16x32_bf16(a0, bfr[j], acc[nh * 8 + j], 0, 0, 0);
      }
      __syncthreads();
    }
  }
  float* aAs = R1f;               // [64][65] f32
  float* bxs = aAs + 64 * 65;     // [64][65] f32
  float Av[4], dtbv[4], xpbv[4];
#pragma unroll
  for (int ni = 0; ni < 4; ni++) {
    int s = ni * 16 + l16;
    Av[ni] = -expf(A_log[s]); dtbv[ni] = dt_b[s]; xpbv[ni] = xp_b[s];
  }
#pragma unroll
  for (int r = 0; r < 4; r++) {
    int lm = w * 16 + quad * 4 + r;
    int m = m0 + lm;
#pragma unroll
    for (int ni = 0; ni < 4; ni++) {
      int s = ni * 16 + l16;
      float z = acc[ni][r] + dtbv[ni];
      float sp = (z > 20.f) ? z : log1pf(expf(z));
      float delta = sp * 0.01f + 0.0001f;
      float bt  = acc[ni + 4][r];
      float ct  = acc[ni + 8][r];
      float xpv = acc[ni + 12][r] + xpbv[ni];
      float dA = fminf(fmaxf(delta * Av[ni], -10.f), -0.0001f);
      float Ae = fminf(fmaxf(expf(dA), 0.001f), 0.999f) + 1e-10f;
      short bxh = f2b(delta * bt * xpv);
      aA[(size_t)m * 64 + s] = Ae;
      unsigned pk = (unsigned)(unsigned short)bxh
                  | ((unsigned)(unsigned short)f2b(ct) << 16);
      bxc[(size_t)m * 64 + s] = pk;
      aAs[lm * 65 + s] = Ae;
      bxs[lm * 65 + s] = b2f(bxh);
    }
  }
  __syncthreads();
  int s = tid & 63, seg = tid >> 6, chunk = seg >> 1, sub = seg & 1;
  bool first = ((m0 & 4095) == 0) && (chunk == 0) && (sub == 0);
  float P = 1.f, H = 0.f;
  int base = chunk * 32 + sub * 16;
#pragma unroll
  for (int j = 0; j < 16; j++) {
    float a  = aAs[(base + j) * 65 + s];
    float bx = bxs[(base + j) * 65 + s];
    if (first && j == 0) { P = a; H = bx; }
    else { P *= a; H = a * (H + bx); }
  }
  float* partP = (float*)R2s;
  float* partH = partP + 256;
  partP[seg * 64 + s] = P; partH[seg * 64 + s] = H;
  __syncthreads();
  if (tid < 128) {
    int c = tid >> 6;
    float p0 = partP[(c * 2) * 64 + s], p1 = partP[(c * 2 + 1) * 64 + s];
    float h0 = partH[(c * 2) * 64 + s], h1 = partH[(c * 2 + 1) * 64 + s];
    int ci = (m0 >> 12) * 128 + ((m0 & 4095) >> 5) + c;
    sums[(ci * 2 + 0) * 64 + s] = p0 * p1;
    sums[(ci * 2 + 1) * 64 + s] = p1 * h0 + h1;
  }
}

// ---- K2: conv (x<192) + scan phase 2 (x==192) merged -----------------------
__global__ __launch_bounds__(256) void k_conv(
    const float* __restrict__ x, const float* __restrict__ dw,
    const float* __restrict__ bn_g, const float* __restrict__ bn_b,
    const float* __restrict__ bn_rm, const float* __restrict__ bn_rv,
    const float* __restrict__ a_loc, float* __restrict__ xr,
    const float* __restrict__ sums, float* __restrict__ carries) {
  __shared__ __align__(16) float xs[64 * 64];
  int tid = threadIdx.x;
  if (blockIdx.x == 192) {
    float* Pp = xs;            // [4][64]
    float* Hp = xs + 256;      // [4][64]
    int b = blockIdx.y, s = tid & 63, q = tid >> 6;
    float P = 1.f, H = 0.f;
#pragma unroll 4
    for (int j = 0; j < 32; j++) {
      int ci = b * 128 + q * 32 + j;
      float a = sums[(ci * 2 + 0) * 64 + s];
      float h = sums[(ci * 2 + 1) * 64 + s];
      P *= a; H = a * H + h;
    }
    Pp[q * 64 + s] = P; Hp[q * 64 + s] = H;
    __syncthreads();
    float cur = 0.f;
    for (int qq = 0; qq < q; qq++) cur = Pp[qq * 64 + s] * cur + Hp[qq * 64 + s];
#pragma unroll 4
    for (int j = 0; j < 32; j++) {
      int ci = b * 128 + q * 32 + j;
      carries[ci * 64 + s] = cur;
      float a = sums[(ci * 2 + 0) * 64 + s];
      float h = sums[(ci * 2 + 1) * 64 + s];
      cur = a * cur + h;
    }
    return;
  }
  int d = blockIdx.x, b = blockIdx.y;
  const float* xp = x + ((size_t)b * Dm + d) * Ln;
  for (int i = tid; i < 1024; i += 256) ((float4*)xs)[i] = ((const float4*)xp)[i];
  __syncthreads();
  float w[9];
#pragma unroll
  for (int k = 0; k < 9; k++) w[k] = dw[d * 9 + k];
  float scale = bn_g[d] * rsqrtf(bn_rv[d] + 1e-5f);
  float rm = bn_rm[d], bb = bn_b[d];
  float al = a_loc[0];
  float* xo = xr + ((size_t)b * Dm + d) * Ln;
  for (int i = tid; i < 4096; i += 256) {
    int h = i >> 6, wc = i & 63;
    float acc = 0.f;
#pragma unroll
    for (int kh = 0; kh < 3; kh++) {
      int hh = h + kh - 1;
      if (hh < 0 || hh >= 64) continue;
#pragma unroll
      for (int kw = 0; kw < 3; kw++) {
        int ww2 = wc + kw - 1;
        if (ww2 < 0 || ww2 >= 64) continue;
        acc += xs[hh * 64 + ww2] * w[kh * 3 + kw];
      }
    }
    float xl = (acc - rm) * scale + bb;
    xo[i] = xs[i] + al * xl;
  }
}

// ---- K3: fused scan replay + out-proj + combine (RMW xr) + LN2 -> xn2 ------
__global__ __launch_bounds__(256) void k_out(
    const float* __restrict__ aA, const unsigned* __restrict__ bxc,
    const float* __restrict__ carries,
    const short* __restrict__ owb, const float* __restrict__ out_b,
    const float* __restrict__ Dp, const short* __restrict__ xln1b,
    const float* __restrict__ a_ssm, const float* __restrict__ g2,
    const float* __restrict__ bb2,
    float* __restrict__ xr, short* __restrict__ xn2) {
  __shared__ __align__(16) float smemf[64 * 193];  // 49.4 KB, aliased
  short* As = (short*)smemf;            // [192][72] bf16
  short* Bs = (short*)smemf + 192 * 72; // [64][72] bf16
  float* tile = smemf;                  // [64][193] f32 (post-MFMA)
  int l0g = blockIdx.x * 64, tid = threadIdx.x;
  int lane = tid & 63, l16 = lane & 15, quad = lane >> 4, wv = tid >> 6;
  for (int i = tid; i < 1536; i += 256) {
    int row = i >> 3, c8 = (i & 7) * 8;
    *(float4*)&As[row * 72 + c8] = *(const float4*)&owb[row * 64 + c8];
  }
  int bb = l0g >> 12, c0 = (l0g & 4095) >> 5;
  float xrv[3][4][4];
#pragma unroll
  for (int mi = 0; mi < 3; mi++)
#pragma unroll
    for (int r = 0; r < 4; r++) {
      int d = wv * 48 + mi * 16 + quad * 4 + r;
#pragma unroll
      for (int ni = 0; ni < 4; ni++) {
        int l = l0g + ni * 16 + l16;
        xrv[mi][r][ni] = xr[((size_t)bb * Dm + d) * Ln + (l & 4095)];
      }
    }
  if (wv < 2) {
    int c = c0 + wv, s = lane;
    float h = carries[(bb * 128 + c) * 64 + s];
    const float* ap = aA + (size_t)(l0g + wv * 32) * 64;
    const unsigned* bp = bxc + (size_t)(l0g + wv * 32) * 64;
    int t = 0;
    if (c == 0) {
      unsigned u = bp[s];
      h = b2f((short)(u & 0xFFFF));
      Bs[(wv * 32) * 72 + s] = f2b(b2f((short)(u >> 16)) * h);
      t = 1;
    }
#pragma unroll 4
    for (; t < 32; t++) {
      unsigned u = bp[t * 64 + s];
      float a = ap[t * 64 + s];
      h = a * (h + b2f((short)(u & 0xFFFF)));
      Bs[(wv * 32 + t) * 72 + s] = f2b(b2f((short)(u >> 16)) * h);
    }
  }
  __syncthreads();
  f32x4 acc[3][4] = {};
#pragma unroll
  for (int ks = 0; ks < 2; ks++) {
    int ko = ks * 32 + quad * 8;
    bf16x8 a[3], b[4];
#pragma unroll
    for (int mi = 0; mi < 3; mi++) a[mi] = *(const bf16x8*)&As[(wv * 48 + mi * 16 + l16) * 72 + ko];
#pragma unroll
    for (int ni = 0; ni < 4; ni++) b[ni] = *(const bf16x8*)&Bs[(ni * 16 + l16) * 72 + ko];
#pragma unroll
    for (int mi = 0; mi < 3; mi++)
#pragma unroll
      for (int ni = 0; ni < 4; ni++)
        acc[mi][ni] = __builtin_amdgcn_mfma_f32_16x16x32_bf16(a[mi], b[ni], acc[mi][ni], 0, 0, 0);
  }
  __syncthreads();
  float as_ = a_ssm[0];
#pragma unroll
  for (int mi = 0; mi < 3; mi++)
#pragma unroll
    for (int r = 0; r < 4; r++) {
      int d = wv * 48 + mi * 16 + quad * 4 + r;
      float ob = out_b[d];
      float dc = fminf(fmaxf(Dp[d], -2.f), 2.f);
#pragma unroll
      for (int ni = 0; ni < 4; ni++) {
        int l = l0g + ni * 16 + l16;
        float v = acc[mi][ni][r] + ob;
        if (dc != 0.f) v += dc * b2f(xln1b[(size_t)l * 192 + d]);
        size_t idx = ((size_t)bb * Dm + d) * Ln + (l & 4095);
        float nx = xrv[mi][r][ni] + as_ * v;
        xr[idx] = nx;
        tile[(l & 63) * 193 + d] = nx;
      }
    }
  __syncthreads();
  int pix = tid >> 2, part = tid & 3, c0p = part * 48;
  float vv[48];
  float s1 = 0.f, q1 = 0.f;
#pragma unroll
  for (int j = 0; j < 48; j++) {
    float t = tile[pix * 193 + c0p + j];
    vv[j] = t; s1 += t; q1 += t * t;
  }
  s1 += __shfl_xor(s1, 1); s1 += __shfl_xor(s1, 2);
  q1 += __shfl_xor(q1, 1); q1 += __shfl_xor(q1, 2);
  float m = s1 * (1.f / 192.f);
  float inv = rsqrtf(q1 * (1.f / 192.f) - m * m + 1e-5f);
  size_t obase = (size_t)(l0g + pix) * Dm + c0p;
#pragma unroll
  for (int j = 0; j < 48; j += 8) {
    int4 no; short* np = (short*)&no;
#pragma unroll
    for (int k = 0; k < 8; k++)
      np[k] = f2b((vv[j + k] - m) * inv * g2[c0p + j + k] + bb2[c0p + j + k]);
    *(int4*)&xn2[obase + j] = no;
  }
}

// ---- K4: MFMA GEMM1, 64x64 tile, single-stage (2 barriers), grid 6144 ------
__global__ __launch_bounds__(256) void k_gemm1(
    const short* __restrict__ xn2, const short* __restrict__ w1b,
    const float* __restrict__ b1h, short* __restrict__ hid) {
  __shared__ __align__(16) short As[64 * 200];  // 25.6 KB pixels (Cs aliases)
  __shared__ __align__(16) short Bs[64 * 200];  // 25.6 KB w1 rows
  int bid = blockIdx.x;
  int xcd = bid & 7, p = bid >> 3;          // p: 0..767
  int m0 = (xcd * 64 + p / 12) * 64, n0 = (p % 12) * 64;
  int tid = threadIdx.x;
  int lane = tid & 63, l16 = lane & 15, quad = lane >> 4, wv = tid >> 6;
  for (int i = tid; i < 1536; i += 256) {
    int row = i / 24, c8 = (i % 24) * 8;
    *(float4*)&As[row * 200 + c8] = *(const float4*)&xn2[(size_t)(m0 + row) * 192 + c8];
    *(float4*)&Bs[row * 200 + c8] = *(const float4*)&w1b[(size_t)(n0 + row) * 192 + c8];
  }
  __syncthreads();
  f32x4 acc[4] = {};
#pragma unroll
  for (int ks = 0; ks < 6; ks++) {
    int ko = ks * 32 + quad * 8;
    bf16x8 a0 = *(const bf16x8*)&As[(wv * 16 + l16) * 200 + ko];
#pragma unroll
    for (int ni = 0; ni < 4; ni++) {
      bf16x8 b0 = *(const bf16x8*)&Bs[(ni * 16 + l16) * 200 + ko];
      acc[ni] = __builtin_amdgcn_mfma_f32_16x16x32_bf16(a0, b0, acc[ni], 0, 0, 0);
    }
  }
  __syncthreads();  // As/Bs reads done -> Cs may alias As
  short* Cs = As;   // [64][72], 9.2 KB
  float bias4[4];
#pragma unroll
  for (int ni = 0; ni < 4; ni++) bias4[ni] = b1h[n0 + ni * 16 + l16];
#pragma unroll
  for (int ni = 0; ni < 4; ni++) {
    int n = ni * 16 + l16;
#pragma unroll
    for (int r = 0; r < 4; r++) {
      int m = wv * 16 + quad * 4 + r;
      float v = acc[ni][r] + bias4[ni];
      // sigmoid-form tanh gelu
      float w2v = v * v;
      float inner = __builtin_fmaf(0.044715f * w2v, v, v);
      float e = exp2f(2.3021183f * inner);
      float g = v - __fdividef(v, 1.f + e);
      Cs[m * 72 + n] = f2b(g);
    }
  }
  __syncthreads();
  for (int i = tid; i < 512; i += 256) {
    int m = i >> 3, ch = i & 7;
    *(float4*)&hid[(size_t)(m0 + m) * 768 + n0 + ch * 8] = *(const float4*)&Cs[m * 72 + ch * 8];
  }
}

// ---- K5: MFMA GEMM2, XCD-swizzled flat grid 1024, xr prefetched ------------
__global__ __launch_bounds__(256) void k_gemm2(
    const short* __restrict__ hid, const short* __restrict__ w2b,
    const float* __restrict__ b2o, const float* __restrict__ xr,
    const float* __restrict__ am, float* __restrict__ out) {
  __shared__ __align__(16) short Wt[96 * 72];
  __shared__ __align__(16) short Ht[64 * 72];
  int bid = blockIdx.x;
  int xcd = bid & 7, p = bid >> 3;          // p: 0..127
  int l0g = (xcd * 64 + (p >> 1)) * 64, d0 = (p & 1) * 96;
  int tid = threadIdx.x;
  int lane = tid & 63, l16 = lane & 15, quad = lane >> 4;
  int wm = (tid >> 6) >> 1, wn = (tid >> 6) & 1;
  float xrv[3][2][4];
#pragma unroll
  for (int mi = 0; mi < 3; mi++)
#pragma unroll
    for (int r = 0; r < 4; r++) {
      int d = d0 + wm * 48 + mi * 16 + quad * 4 + r;
#pragma unroll
      for (int ni = 0; ni < 2; ni++) {
        int lg = l0g + wn * 32 + ni * 16 + l16;
        xrv[mi][ni][r] = xr[((size_t)(lg >> 12) * Dm + d) * Ln + (lg & 4095)];
      }
    }
  f32x4 acc[3][2] = {};
  for (int kt = 0; kt < 12; kt++) {
    int kb = kt * 64;
    for (int i = tid; i < 768; i += 256) {
      int row = i >> 3, c8 = (i & 7) * 8;
      *(float4*)&Wt[row * 72 + c8] = *(const float4*)&w2b[(size_t)(d0 + row) * 768 + kb + c8];
    }
    for (int i = tid; i < 512; i += 256) {
      int row = i >> 3, c8 = (i & 7) * 8;
      *(float4*)&Ht[row * 72 + c8] = *(const float4*)&hid[(size_t)(l0g + row) * 768 + kb + c8];
    }
    __syncthreads();
#pragma unroll
    for (int ks = 0; ks < 2; ks++) {
      int ko = ks * 32 + quad * 8;
      bf16x8 a[3], b[2];
#pragma unroll
      for (int mi = 0; mi < 3; mi++) a[mi] = *(const bf16x8*)&Wt[(wm * 48 + mi * 16 + l16) * 72 + ko];
#pragma unroll
      for (int ni = 0; ni < 2; ni++) b[ni] = *(const bf16x8*)&Ht[(wn * 32 + ni * 16 + l16) * 72 + ko];
#pragma unroll
      for (int mi = 0; mi < 3; mi++)
#pragma unroll
        for (int ni = 0; ni < 2; ni++)
          acc[mi][ni] = __builtin_amdgcn_mfma_f32_16x16x32_bf16(a[mi], b[ni], acc[mi][ni], 0, 0, 0);
    }
    __syncthreads();
  }
  float alpha = am[0];
#pragma unroll
  for (int mi = 0; mi < 3; mi++)
#pragma unroll
    for (int r = 0; r < 4; r++) {
      int d = d0 + wm * 48 + mi * 16 + quad * 4 + r;
      float bias = b2o[d];
#pragma unroll
      for (int ni = 0; ni < 2; ni++) {
        int lg = l0g + wn * 32 + ni * 16 + l16;
        size_t idx = ((size_t)(lg >> 12) * Dm + d) * Ln + (lg & 4095);
        out[idx] = xrv[mi][ni][r] + alpha * (acc[mi][ni][r] + bias);
      }
    }
}

extern "C" void kernel_launch(void* const* d_in, const int* in_sizes, int n_in,
                              void* d_out, int out_size, void* d_ws, size_t ws_size,
                              hipStream_t stream) {
  (void)in_sizes; (void)n_in; (void)out_size; (void)ws_size;
  const float* x     = (const float*)d_in[0];
  const float* ln1_g = (const float*)d_in[1];
  const float* ln1_b = (const float*)d_in[2];
  const float* ln2_g = (const float*)d_in[3];
  const float* ln2_b = (const float*)d_in[4];
  const float* dw_w  = (const float*)d_in[5];
  const float* bn_g  = (const float*)d_in[6];
  const float* bn_b  = (const float*)d_in[7];
  const float* bn_rm = (const float*)d_in[8];
  const float* bn_rv = (const float*)d_in[9];
  const float* ssm_g = (const float*)d_in[10];
  const float* ssm_b = (const float*)d_in[11];
  const float* xp_w  = (const float*)d_in[12];
  const float* xp_b  = (const float*)d_in[13];
  const float* dt_w  = (const float*)d_in[14];
  const float* dt_b  = (const float*)d_in[15];
  const float* A_log = (const float*)d_in[16];
  const float* B_w   = (const float*)d_in[17];
  const float* C_w   = (const float*)d_in[18];
  const float* Dp    = (const float*)d_in[19];
  const float* out_w = (const float*)d_in[20];
  const float* out_b = (const float*)d_in[21];
  const float* w1    = (const float*)d_in[22];
  const float* b1    = (const float*)d_in[23];
  const float* w2    = (const float*)d_in[24];
  const float* b2    = (const float*)d_in[25];
  const float* a_loc = (const float*)d_in[26];
  const float* a_ssm = (const float*)d_in[27];
  const float* a_mlp = (const float*)d_in[28];

  float* ws = (float*)d_ws;
  short*    xln1b = (short*)(ws + 3145728);        // [32768,192] bf16
  float*    aA    = ws + 6291456;                  // [32768,64] f32
  unsigned* bxc   = (unsigned*)(ws + 8388608);     // [32768,64] packed bf16x2
  float*    xr    = ws + 17825792;                 // [8,192,4096] f32
  short*    wb    = (short*)(ws + 24117248);       // bf16 weights
  float*    sums  = ws + 24829952;                 // 131072 f
  float*    carr  = ws + 24961024;                 // 65536 f
  short*    xn2   = (short*)(ws + 25026560);       // [32768,192] bf16
  short*    hid   = (short*)(ws + 28172288);       // [32768,768] bf16
  short*    wcatb = wb;            // [256,192] = dt|B|C|xp rows
  short*    owb   = wb + 49152;    // [192,64]
  short*    w1b   = wb + 61440;    // [768,192]
  short*    w2b   = wb + 208896;   // [192,768]
  float*    out   = (float*)d_out;

  k_weights<<<dim3(64),     256, 0, stream>>>(dt_w, B_w, C_w, xp_w, out_w, w1, w2, wb);
  k_fproj  <<<dim3(512),    256, 0, stream>>>(x, ln1_g, ln1_b, ssm_g, ssm_b, xln1b,
                                              wcatb, dt_b, xp_b, A_log, aA, bxc, sums);
  k_conv   <<<dim3(193, 8), 256, 0, stream>>>(x, dw_w, bn_g, bn_b, bn_rm, bn_rv, a_loc, xr,
                                              sums, carr);
  k_out    <<<dim3(512),    256, 0, stream>>>(aA, bxc, carr, owb, out_b, Dp, xln1b,
                                              a_ssm, ln2_g, ln2_b, xr, xn2);
  k_gemm1  <<<dim3(6144),   256, 0, stream>>>(xn2, w1b, b1, hid);
  k_gemm2  <<<dim3(1024),   256, 0, stream>>>(hid, w2b, b2, xr, a_mlp, out);
}

// Round 16
// 253.432 us; speedup vs baseline: 1.0381x; 1.0381x over previous
//
#include <hip/hip_runtime.h>
#include <hip/hip_bf16.h>
#include <math.h>

// MambaBlock v24: restore v22 (best measured, 257.6-258.2µs).
//  R15 lesson: gemm1 at 128x64/5-blk-per-CU is a local optimum (~40µs);
//  both more phases (v15-style) and fewer phases (v23 single-stage) lose
//  more occupancy than they save in barriers. Fused MLP ruled out (w2
//  A-operand re-staging -> 88KB LDS -> 1 blk/CU). hid round-trip is right.
//  Only tweak vs v22: k_weights one-pass grid (348 blocks).
// Dispatches: 6.

#define DEV static __device__ __forceinline__

constexpr int Bn = 8, Dm = 192, Ln = 4096, Sn = 64, Hd = 768;

typedef __attribute__((ext_vector_type(8))) short bf16x8;
typedef __attribute__((ext_vector_type(4))) float f32x4;

DEV short f2b(float x) {
  __hip_bfloat16 h = __float2bfloat16(x);
  return *(short*)&h;
}

DEV float b2f(short x) {
  __hip_bfloat16 h = *(__hip_bfloat16*)&x;
  return __bfloat162float(h);
}

// ---- K0: weight f32 -> bf16 conversion, one pass ---------------------------
__global__ __launch_bounds__(256) void k_weights(
    const float* __restrict__ dt_w, const float* __restrict__ B_w,
    const float* __restrict__ C_w, const float* __restrict__ xp_w,
    const float* __restrict__ out_w, const float* __restrict__ w1,
    const float* __restrict__ w2, short* __restrict__ wb) {
  int i = blockIdx.x * 256 + threadIdx.x;
  if (i >= 89088) return;
  const float4* src;
  if (i < 3072)       src = (const float4*)dt_w + i;
  else if (i < 6144)  src = (const float4*)B_w + (i - 3072);
  else if (i < 9216)  src = (const float4*)C_w + (i - 6144);
  else if (i < 12288) src = (const float4*)xp_w + (i - 9216);
  else if (i < 15360) src = (const float4*)out_w + (i - 12288);
  else if (i < 52224) src = (const float4*)w1 + (i - 15360);
  else                src = (const float4*)w2 + (i - 52224);
  float4 v = *src;
  int o = i * 4;
  wb[o] = f2b(v.x); wb[o + 1] = f2b(v.y); wb[o + 2] = f2b(v.z); wb[o + 3] = f2b(v.w);
}

// ---- K1: fused LN1+ssmLN + proj GEMM + SSM epilogue + scan ph1 -------------
__global__ __launch_bounds__(256, 3) void k_fproj(
    const float* __restrict__ x,
    const float* __restrict__ g1, const float* __restrict__ b1,
    const float* __restrict__ g2, const float* __restrict__ b2,
    short* __restrict__ xln1b,
    const short* __restrict__ wcat,
    const float* __restrict__ dt_b, const float* __restrict__ xp_b,
    const float* __restrict__ A_log, float* __restrict__ aA, unsigned* __restrict__ bxc,
    float* __restrict__ sums) {
  __shared__ __align__(16) float R1f[8320];       // 33.3 KB: As (25.6K) / aAs+bxs
  __shared__ __align__(16) short R2s[128 * 72];   // 18.4 KB: Bs half / partP+H
  short* As = (short*)R1f;     // [64][200] bf16 xn tile
  short* Bs = R2s;             // [128][72] bf16 wcat half
  int m0 = blockIdx.x * 64, tid = threadIdx.x;
  int b = m0 >> 12, l0 = m0 & 4095;
  {
    int pix = tid >> 2, part = tid & 3, c0 = part * 48;
    const float* xb = x + (size_t)b * Dm * Ln + l0 + pix;
    float v[48];
    float s1 = 0.f, q1 = 0.f;
#pragma unroll
    for (int j = 0; j < 48; j++) {
      float t = xb[(size_t)(c0 + j) * Ln];
      v[j] = t; s1 += t; q1 += t * t;
    }
    s1 += __shfl_xor(s1, 1); s1 += __shfl_xor(s1, 2);
    q1 += __shfl_xor(q1, 1); q1 += __shfl_xor(q1, 2);
    float m = s1 * (1.f / 192.f);
    float inv = rsqrtf(q1 * (1.f / 192.f) - m * m + 1e-5f);
    float s2 = 0.f, q2 = 0.f;
#pragma unroll
    for (int j = 0; j < 48; j++) {
      float y = (v[j] - m) * inv * g1[c0 + j] + b1[c0 + j];
      v[j] = y; s2 += y; q2 += y * y;
    }
    s2 += __shfl_xor(s2, 1); s2 += __shfl_xor(s2, 2);
    q2 += __shfl_xor(q2, 1); q2 += __shfl_xor(q2, 2);
    float m2 = s2 * (1.f / 192.f);
    float inv2 = rsqrtf(q2 * (1.f / 192.f) - m2 * m2 + 1e-5f);
    size_t base = (size_t)(m0 + pix) * Dm + c0;
#pragma unroll
    for (int j = 0; j < 48; j += 8) {
      int4 yo, no;
      short* yp = (short*)&yo; short* np = (short*)&no;
#pragma unroll
      for (int k = 0; k < 8; k++) {
        float y = v[j + k];
        yp[k] = f2b(y);
        np[k] = f2b((y - m2) * inv2 * g2[c0 + j + k] + b2[c0 + j + k]);
      }
      *(int4*)&xln1b[base + j] = yo;
      *(int4*)&As[pix * 200 + c0 + j] = no;
    }
  }
  __syncthreads();
  int lane = tid & 63, l16 = lane & 15, quad = lane >> 4, w = tid >> 6;
  f32x4 acc[16] = {};
  for (int kt = 0; kt < 3; kt++) {
    int kb = kt * 64;
#pragma unroll
    for (int nh = 0; nh < 2; nh++) {
      for (int i = tid; i < 1024; i += 256) {
        int row = i >> 3, c8 = (i & 7) * 8;
        *(float4*)&Bs[row * 72 + c8] =
            *(const float4*)&wcat[(size_t)(nh * 128 + row) * 192 + kb + c8];
      }
      __syncthreads();
#pragma unroll
      for (int ks = 0; ks < 2; ks++) {
        int ko = ks * 32 + quad * 8;
        bf16x8 a0 = *(const bf16x8*)&As[(w * 16 + l16) * 200 + kb + ko];
        bf16x8 bfr[8];
#pragma unroll
        for (int j = 0; j < 8; j++) bfr[j] = *(const bf16x8*)&Bs[(j * 16 + l16) * 72 + ko];
#pragma unroll
        for (int j = 0; j < 8; j++)
          acc[nh * 8 + j] = __builtin_amdgcn_mfma_f32_16x16x32_bf16(a0, bfr[j], acc[nh * 8 + j], 0, 0, 0);
      }
      __syncthreads();
    }
  }
  float* aAs = R1f;               // [64][65] f32
  float* bxs = aAs + 64 * 65;     // [64][65] f32
  float Av[4], dtbv[4], xpbv[4];
#pragma unroll
  for (int ni = 0; ni < 4; ni++) {
    int s = ni * 16 + l16;
    Av[ni] = -expf(A_log[s]); dtbv[ni] = dt_b[s]; xpbv[ni] = xp_b[s];
  }
#pragma unroll
  for (int r = 0; r < 4; r++) {
    int lm = w * 16 + quad * 4 + r;
    int m = m0 + lm;
#pragma unroll
    for (int ni = 0; ni < 4; ni++) {
      int s = ni * 16 + l16;
      float z = acc[ni][r] + dtbv[ni];
      float sp = (z > 20.f) ? z : log1pf(expf(z));
      float delta = sp * 0.01f + 0.0001f;
      float bt  = acc[ni + 4][r];
      float ct  = acc[ni + 8][r];
      float xpv = acc[ni + 12][r] + xpbv[ni];
      float dA = fminf(fmaxf(delta * Av[ni], -10.f), -0.0001f);
      float Ae = fminf(fmaxf(expf(dA), 0.001f), 0.999f) + 1e-10f;
      short bxh = f2b(delta * bt * xpv);
      aA[(size_t)m * 64 + s] = Ae;
      unsigned pk = (unsigned)(unsigned short)bxh
                  | ((unsigned)(unsigned short)f2b(ct) << 16);
      bxc[(size_t)m * 64 + s] = pk;
      aAs[lm * 65 + s] = Ae;
      bxs[lm * 65 + s] = b2f(bxh);
    }
  }
  __syncthreads();
  int s = tid & 63, seg = tid >> 6, chunk = seg >> 1, sub = seg & 1;
  bool first = ((m0 & 4095) == 0) && (chunk == 0) && (sub == 0);
  float P = 1.f, H = 0.f;
  int base = chunk * 32 + sub * 16;
#pragma unroll
  for (int j = 0; j < 16; j++) {
    float a  = aAs[(base + j) * 65 + s];
    float bx = bxs[(base + j) * 65 + s];
    if (first && j == 0) { P = a; H = bx; }
    else { P *= a; H = a * (H + bx); }
  }
  float* partP = (float*)R2s;
  float* partH = partP + 256;
  partP[seg * 64 + s] = P; partH[seg * 64 + s] = H;
  __syncthreads();
  if (tid < 128) {
    int c = tid >> 6;
    float p0 = partP[(c * 2) * 64 + s], p1 = partP[(c * 2 + 1) * 64 + s];
    float h0 = partH[(c * 2) * 64 + s], h1 = partH[(c * 2 + 1) * 64 + s];
    int ci = (m0 >> 12) * 128 + ((m0 & 4095) >> 5) + c;
    sums[(ci * 2 + 0) * 64 + s] = p0 * p1;
    sums[(ci * 2 + 1) * 64 + s] = p1 * h0 + h1;
  }
}

// ---- K2: conv (x<192) + scan phase 2 (x==192) merged -----------------------
__global__ __launch_bounds__(256) void k_conv(
    const float* __restrict__ x, const float* __restrict__ dw,
    const float* __restrict__ bn_g, const float* __restrict__ bn_b,
    const float* __restrict__ bn_rm, const float* __restrict__ bn_rv,
    const float* __restrict__ a_loc, float* __restrict__ xr,
    const float* __restrict__ sums, float* __restrict__ carries) {
  __shared__ __align__(16) float xs[64 * 64];
  int tid = threadIdx.x;
  if (blockIdx.x == 192) {
    float* Pp = xs;            // [4][64]
    float* Hp = xs + 256;      // [4][64]
    int b = blockIdx.y, s = tid & 63, q = tid >> 6;
    float P = 1.f, H = 0.f;
#pragma unroll 4
    for (int j = 0; j < 32; j++) {
      int ci = b * 128 + q * 32 + j;
      float a = sums[(ci * 2 + 0) * 64 + s];
      float h = sums[(ci * 2 + 1) * 64 + s];
      P *= a; H = a * H + h;
    }
    Pp[q * 64 + s] = P; Hp[q * 64 + s] = H;
    __syncthreads();
    float cur = 0.f;
    for (int qq = 0; qq < q; qq++) cur = Pp[qq * 64 + s] * cur + Hp[qq * 64 + s];
#pragma unroll 4
    for (int j = 0; j < 32; j++) {
      int ci = b * 128 + q * 32 + j;
      carries[ci * 64 + s] = cur;
      float a = sums[(ci * 2 + 0) * 64 + s];
      float h = sums[(ci * 2 + 1) * 64 + s];
      cur = a * cur + h;
    }
    return;
  }
  int d = blockIdx.x, b = blockIdx.y;
  const float* xp = x + ((size_t)b * Dm + d) * Ln;
  for (int i = tid; i < 1024; i += 256) ((float4*)xs)[i] = ((const float4*)xp)[i];
  __syncthreads();
  float w[9];
#pragma unroll
  for (int k = 0; k < 9; k++) w[k] = dw[d * 9 + k];
  float scale = bn_g[d] * rsqrtf(bn_rv[d] + 1e-5f);
  float rm = bn_rm[d], bb = bn_b[d];
  float al = a_loc[0];
  float* xo = xr + ((size_t)b * Dm + d) * Ln;
  for (int i = tid; i < 4096; i += 256) {
    int h = i >> 6, wc = i & 63;
    float acc = 0.f;
#pragma unroll
    for (int kh = 0; kh < 3; kh++) {
      int hh = h + kh - 1;
      if (hh < 0 || hh >= 64) continue;
#pragma unroll
      for (int kw = 0; kw < 3; kw++) {
        int ww2 = wc + kw - 1;
        if (ww2 < 0 || ww2 >= 64) continue;
        acc += xs[hh * 64 + ww2] * w[kh * 3 + kw];
      }
    }
    float xl = (acc - rm) * scale + bb;
    xo[i] = xs[i] + al * xl;
  }
}

// ---- K3: fused scan replay + out-proj + combine (RMW xr) + LN2 -> xn2 ------
__global__ __launch_bounds__(256) void k_out(
    const float* __restrict__ aA, const unsigned* __restrict__ bxc,
    const float* __restrict__ carries,
    const short* __restrict__ owb, const float* __restrict__ out_b,
    const float* __restrict__ Dp, const short* __restrict__ xln1b,
    const float* __restrict__ a_ssm, const float* __restrict__ g2,
    const float* __restrict__ bb2,
    float* __restrict__ xr, short* __restrict__ xn2) {
  __shared__ __align__(16) float smemf[64 * 193];  // 49.4 KB, aliased
  short* As = (short*)smemf;            // [192][72] bf16
  short* Bs = (short*)smemf + 192 * 72; // [64][72] bf16
  float* tile = smemf;                  // [64][193] f32 (post-MFMA)
  int l0g = blockIdx.x * 64, tid = threadIdx.x;
  int lane = tid & 63, l16 = lane & 15, quad = lane >> 4, wv = tid >> 6;
  for (int i = tid; i < 1536; i += 256) {
    int row = i >> 3, c8 = (i & 7) * 8;
    *(float4*)&As[row * 72 + c8] = *(const float4*)&owb[row * 64 + c8];
  }
  int bb = l0g >> 12, c0 = (l0g & 4095) >> 5;
  float xrv[3][4][4];
#pragma unroll
  for (int mi = 0; mi < 3; mi++)
#pragma unroll
    for (int r = 0; r < 4; r++) {
      int d = wv * 48 + mi * 16 + quad * 4 + r;
#pragma unroll
      for (int ni = 0; ni < 4; ni++) {
        int l = l0g + ni * 16 + l16;
        xrv[mi][r][ni] = xr[((size_t)bb * Dm + d) * Ln + (l & 4095)];
      }
    }
  if (wv < 2) {
    int c = c0 + wv, s = lane;
    float h = carries[(bb * 128 + c) * 64 + s];
    const float* ap = aA + (size_t)(l0g + wv * 32) * 64;
    const unsigned* bp = bxc + (size_t)(l0g + wv * 32) * 64;
    int t = 0;
    if (c == 0) {
      unsigned u = bp[s];
      h = b2f((short)(u & 0xFFFF));
      Bs[(wv * 32) * 72 + s] = f2b(b2f((short)(u >> 16)) * h);
      t = 1;
    }
#pragma unroll 4
    for (; t < 32; t++) {
      unsigned u = bp[t * 64 + s];
      float a = ap[t * 64 + s];
      h = a * (h + b2f((short)(u & 0xFFFF)));
      Bs[(wv * 32 + t) * 72 + s] = f2b(b2f((short)(u >> 16)) * h);
    }
  }
  __syncthreads();
  f32x4 acc[3][4] = {};
#pragma unroll
  for (int ks = 0; ks < 2; ks++) {
    int ko = ks * 32 + quad * 8;
    bf16x8 a[3], b[4];
#pragma unroll
    for (int mi = 0; mi < 3; mi++) a[mi] = *(const bf16x8*)&As[(wv * 48 + mi * 16 + l16) * 72 + ko];
#pragma unroll
    for (int ni = 0; ni < 4; ni++) b[ni] = *(const bf16x8*)&Bs[(ni * 16 + l16) * 72 + ko];
#pragma unroll
    for (int mi = 0; mi < 3; mi++)
#pragma unroll
      for (int ni = 0; ni < 4; ni++)
        acc[mi][ni] = __builtin_amdgcn_mfma_f32_16x16x32_bf16(a[mi], b[ni], acc[mi][ni], 0, 0, 0);
  }
  __syncthreads();
  float as_ = a_ssm[0];
#pragma unroll
  for (int mi = 0; mi < 3; mi++)
#pragma unroll
    for (int r = 0; r < 4; r++) {
      int d = wv * 48 + mi * 16 + quad * 4 + r;
      float ob = out_b[d];
      float dc = fminf(fmaxf(Dp[d], -2.f), 2.f);
#pragma unroll
      for (int ni = 0; ni < 4; ni++) {
        int l = l0g + ni * 16 + l16;
        float v = acc[mi][ni][r] + ob;
        if (dc != 0.f) v += dc * b2f(xln1b[(size_t)l * 192 + d]);
        size_t idx = ((size_t)bb * Dm + d) * Ln + (l & 4095);
        float nx = xrv[mi][r][ni] + as_ * v;
        xr[idx] = nx;
        tile[(l & 63) * 193 + d] = nx;
      }
    }
  __syncthreads();
  int pix = tid >> 2, part = tid & 3, c0p = part * 48;
  float vv[48];
  float s1 = 0.f, q1 = 0.f;
#pragma unroll
  for (int j = 0; j < 48; j++) {
    float t = tile[pix * 193 + c0p + j];
    vv[j] = t; s1 += t; q1 += t * t;
  }
  s1 += __shfl_xor(s1, 1); s1 += __shfl_xor(s1, 2);
  q1 += __shfl_xor(q1, 1); q1 += __shfl_xor(q1, 2);
  float m = s1 * (1.f / 192.f);
  float inv = rsqrtf(q1 * (1.f / 192.f) - m * m + 1e-5f);
  size_t obase = (size_t)(l0g + pix) * Dm + c0p;
#pragma unroll
  for (int j = 0; j < 48; j += 8) {
    int4 no; short* np = (short*)&no;
#pragma unroll
    for (int k = 0; k < 8; k++)
      np[k] = f2b((vv[j + k] - m) * inv * g2[c0p + j + k] + bb2[c0p + j + k]);
    *(int4*)&xn2[obase + j] = no;
  }
}

// ---- K4: MFMA GEMM1, tile 128x64, XCD-swizzled, sigmoid-form gelu ----------
__global__ __launch_bounds__(256) void k_gemm1(
    const short* __restrict__ xn2, const short* __restrict__ w1b,
    const float* __restrict__ b1h, short* __restrict__ hid) {
  __shared__ __align__(16) short smem[128 * 72 + 64 * 72];  // As | Bs, 27.6 KB
  short* As = smem;            // [128][72]
  short* Bs = smem + 128 * 72; // [64][72]
  int bid = blockIdx.x;
  int xcd = bid & 7, p = bid >> 3;          // p: 0..383
  int m0 = (xcd * 32 + p / 12) * 128, n0 = (p % 12) * 64;
  int tid = threadIdx.x;
  int lane = tid & 63, l16 = lane & 15, quad = lane >> 4;
  int wm = (tid >> 6) >> 1, wn = (tid >> 6) & 1;
  f32x4 acc[4][2] = {};
  for (int kt = 0; kt < 3; kt++) {
    int kb = kt * 64;
    for (int i = tid; i < 1024; i += 256) {
      int row = i >> 3, c8 = (i & 7) * 8;
      *(float4*)&As[row * 72 + c8] = *(const float4*)&xn2[(size_t)(m0 + row) * 192 + kb + c8];
    }
    for (int i = tid; i < 512; i += 256) {
      int row = i >> 3, c8 = (i & 7) * 8;
      *(float4*)&Bs[row * 72 + c8] = *(const float4*)&w1b[(size_t)(n0 + row) * 192 + kb + c8];
    }
    __syncthreads();
#pragma unroll
    for (int ks = 0; ks < 2; ks++) {
      int ko = ks * 32 + quad * 8;
      bf16x8 a[4], b[2];
#pragma unroll
      for (int mi = 0; mi < 4; mi++) a[mi] = *(const bf16x8*)&As[(wm * 64 + mi * 16 + l16) * 72 + ko];
#pragma unroll
      for (int ni = 0; ni < 2; ni++) b[ni] = *(const bf16x8*)&Bs[(wn * 32 + ni * 16 + l16) * 72 + ko];
#pragma unroll
      for (int mi = 0; mi < 4; mi++)
#pragma unroll
        for (int ni = 0; ni < 2; ni++)
          acc[mi][ni] = __builtin_amdgcn_mfma_f32_16x16x32_bf16(a[mi], b[ni], acc[mi][ni], 0, 0, 0);
    }
    __syncthreads();
  }
  short* Cs = smem;  // [128][72]
  float bias2[2];
#pragma unroll
  for (int ni = 0; ni < 2; ni++) bias2[ni] = b1h[n0 + wn * 32 + ni * 16 + l16];
#pragma unroll
  for (int mi = 0; mi < 4; mi++)
#pragma unroll
    for (int ni = 0; ni < 2; ni++) {
      int n = wn * 32 + ni * 16 + l16;
#pragma unroll
      for (int r = 0; r < 4; r++) {
        int m = wm * 64 + mi * 16 + quad * 4 + r;
        float v = acc[mi][ni][r] + bias2[ni];
        float w2v = v * v;
        float inner = __builtin_fmaf(0.044715f * w2v, v, v);
        float e = exp2f(2.3021183f * inner);
        float g = v - __fdividef(v, 1.f + e);
        Cs[m * 72 + n] = f2b(g);
      }
    }
  __syncthreads();
  for (int i = tid; i < 1024; i += 256) {
    int m = i >> 3, ch = i & 7;
    *(float4*)&hid[(size_t)(m0 + m) * 768 + n0 + ch * 8] = *(const float4*)&Cs[m * 72 + ch * 8];
  }
}

// ---- K5: MFMA GEMM2, XCD-swizzled flat grid 1024, xr prefetched ------------
__global__ __launch_bounds__(256) void k_gemm2(
    const short* __restrict__ hid, const short* __restrict__ w2b,
    const float* __restrict__ b2o, const float* __restrict__ xr,
    const float* __restrict__ am, float* __restrict__ out) {
  __shared__ __align__(16) short Wt[96 * 72];
  __shared__ __align__(16) short Ht[64 * 72];
  int bid = blockIdx.x;
  int xcd = bid & 7, p = bid >> 3;          // p: 0..127
  int l0g = (xcd * 64 + (p >> 1)) * 64, d0 = (p & 1) * 96;
  int tid = threadIdx.x;
  int lane = tid & 63, l16 = lane & 15, quad = lane >> 4;
  int wm = (tid >> 6) >> 1, wn = (tid >> 6) & 1;
  float xrv[3][2][4];
#pragma unroll
  for (int mi = 0; mi < 3; mi++)
#pragma unroll
    for (int r = 0; r < 4; r++) {
      int d = d0 + wm * 48 + mi * 16 + quad * 4 + r;
#pragma unroll
      for (int ni = 0; ni < 2; ni++) {
        int lg = l0g + wn * 32 + ni * 16 + l16;
        xrv[mi][ni][r] = xr[((size_t)(lg >> 12) * Dm + d) * Ln + (lg & 4095)];
      }
    }
  f32x4 acc[3][2] = {};
  for (int kt = 0; kt < 12; kt++) {
    int kb = kt * 64;
    for (int i = tid; i < 768; i += 256) {
      int row = i >> 3, c8 = (i & 7) * 8;
      *(float4*)&Wt[row * 72 + c8] = *(const float4*)&w2b[(size_t)(d0 + row) * 768 + kb + c8];
    }
    for (int i = tid; i < 512; i += 256) {
      int row = i >> 3, c8 = (i & 7) * 8;
      *(float4*)&Ht[row * 72 + c8] = *(const float4*)&hid[(size_t)(l0g + row) * 768 + kb + c8];
    }
    __syncthreads();
#pragma unroll
    for (int ks = 0; ks < 2; ks++) {
      int ko = ks * 32 + quad * 8;
      bf16x8 a[3], b[2];
#pragma unroll
      for (int mi = 0; mi < 3; mi++) a[mi] = *(const bf16x8*)&Wt[(wm * 48 + mi * 16 + l16) * 72 + ko];
#pragma unroll
      for (int ni = 0; ni < 2; ni++) b[ni] = *(const bf16x8*)&Ht[(wn * 32 + ni * 16 + l16) * 72 + ko];
#pragma unroll
      for (int mi = 0; mi < 3; mi++)
#pragma unroll
        for (int ni = 0; ni < 2; ni++)
          acc[mi][ni] = __builtin_amdgcn_mfma_f32_16x16x32_bf16(a[mi], b[ni], acc[mi][ni], 0, 0, 0);
    }
    __syncthreads();
  }
  float alpha = am[0];
#pragma unroll
  for (int mi = 0; mi < 3; mi++)
#pragma unroll
    for (int r = 0; r < 4; r++) {
      int d = d0 + wm * 48 + mi * 16 + quad * 4 + r;
      float bias = b2o[d];
#pragma unroll
      for (int ni = 0; ni < 2; ni++) {
        int lg = l0g + wn * 32 + ni * 16 + l16;
        size_t idx = ((size_t)(lg >> 12) * Dm + d) * Ln + (lg & 4095);
        out[idx] = xrv[mi][ni][r] + alpha * (acc[mi][ni][r] + bias);
      }
    }
}

extern "C" void kernel_launch(void* const* d_in, const int* in_sizes, int n_in,
                              void* d_out, int out_size, void* d_ws, size_t ws_size,
                              hipStream_t stream) {
  (void)in_sizes; (void)n_in; (void)out_size; (void)ws_size;
  const float* x     = (const float*)d_in[0];
  const float* ln1_g = (const float*)d_in[1];
  const float* ln1_b = (const float*)d_in[2];
  const float* ln2_g = (const float*)d_in[3];
  const float* ln2_b = (const float*)d_in[4];
  const float* dw_w  = (const float*)d_in[5];
  const float* bn_g  = (const float*)d_in[6];
  const float* bn_b  = (const float*)d_in[7];
  const float* bn_rm = (const float*)d_in[8];
  const float* bn_rv = (const float*)d_in[9];
  const float* ssm_g = (const float*)d_in[10];
  const float* ssm_b = (const float*)d_in[11];
  const float* xp_w  = (const float*)d_in[12];
  const float* xp_b  = (const float*)d_in[13];
  const float* dt_w  = (const float*)d_in[14];
  const float* dt_b  = (const float*)d_in[15];
  const float* A_log = (const float*)d_in[16];
  const float* B_w   = (const float*)d_in[17];
  const float* C_w   = (const float*)d_in[18];
  const float* Dp    = (const float*)d_in[19];
  const float* out_w = (const float*)d_in[20];
  const float* out_b = (const float*)d_in[21];
  const float* w1    = (const float*)d_in[22];
  const float* b1    = (const float*)d_in[23];
  const float* w2    = (const float*)d_in[24];
  const float* b2    = (const float*)d_in[25];
  const float* a_loc = (const float*)d_in[26];
  const float* a_ssm = (const float*)d_in[27];
  const float* a_mlp = (const float*)d_in[28];

  float* ws = (float*)d_ws;
  short*    xln1b = (short*)(ws + 3145728);        // [32768,192] bf16
  float*    aA    = ws + 6291456;                  // [32768,64] f32
  unsigned* bxc   = (unsigned*)(ws + 8388608);     // [32768,64] packed bf16x2
  float*    xr    = ws + 17825792;                 // [8,192,4096] f32
  short*    wb    = (short*)(ws + 24117248);       // bf16 weights
  float*    sums  = ws + 24829952;                 // 131072 f
  float*    carr  = ws + 24961024;                 // 65536 f
  short*    xn2   = (short*)(ws + 25026560);       // [32768,192] bf16
  short*    hid   = (short*)(ws + 28172288);       // [32768,768] bf16
  short*    wcatb = wb;            // [256,192] = dt|B|C|xp rows
  short*    owb   = wb + 49152;    // [192,64]
  short*    w1b   = wb + 61440;    // [768,192]
  short*    w2b   = wb + 208896;   // [192,768]
  float*    out   = (float*)d_out;

  k_weights<<<dim3(348),    256, 0, stream>>>(dt_w, B_w, C_w, xp_w, out_w, w1, w2, wb);
  k_fproj  <<<dim3(512),    256, 0, stream>>>(x, ln1_g, ln1_b, ssm_g, ssm_b, xln1b,
                                              wcatb, dt_b, xp_b, A_log, aA, bxc, sums);
  k_conv   <<<dim3(193, 8), 256, 0, stream>>>(x, dw_w, bn_g, bn_b, bn_rm, bn_rv, a_loc, xr,
                                              sums, carr);
  k_out    <<<dim3(512),    256, 0, stream>>>(aA, bxc, carr, owb, out_b, Dp, xln1b,
                                              a_ssm, ln2_g, ln2_b, xr, xn2);
  k_gemm1  <<<dim3(3072),   256, 0, stream>>>(xn2, w1b, b1, hid);
  k_gemm2  <<<dim3(1024),   256, 0, stream>>>(hid, w2b, b2, xr, a_mlp, out);
}